// Round 17
// baseline (240.310 us; speedup 1.0000x reference)
//
#include <hip/hip_runtime.h>
#include <math.h>

#define BB 4
#define HH 64
#define WW 64
#define CC 64
#define NN (HH*WW)          // 4096 pixels per batch
#define NPIX (BB*NN)        // 16384 total pixels
#define EPS 1e-3f
#define QBLK 32
#define KSPLIT 4
#define NQT32 (NPIX/QBLK)   // 512 query tiles of 32
#define NCHK ((NN/KSPLIT)/64)  // 16 chunks of 64 keys per segment
#define GRID 512

using bf16x8 = __attribute__((ext_vector_type(8))) short;
using f32x4  = __attribute__((ext_vector_type(4))) float;
using f32x16 = __attribute__((ext_vector_type(16))) float;

__device__ inline unsigned short bf16bits(float f) {
    union { float f; unsigned u; } a; a.f = f;
    unsigned r = a.u + 0x7fffu + ((a.u >> 16) & 1u);   // RNE
    return (unsigned short)(r >> 16);
}
__device__ inline unsigned packbf(float lo, float hi) {
    return (unsigned)bf16bits(lo) | ((unsigned)bf16bits(hi) << 16);
}
__device__ inline unsigned cvtpk(float lo, float hi) {
    unsigned r;
    asm("v_cvt_pk_bf16_f32 %0, %1, %2" : "=v"(r) : "v"(lo), "v"(hi));
    return r;
}
#define PSWAP(a, b) asm("v_permlane32_swap_b32 %0, %1" : "+v"(a), "+v"(b))

__device__ __forceinline__ float exp2g(float x) {
    float r;
    asm("v_exp_f32 %0, %1" : "=v"(r) : "v"(x));
    return r;
}

// Q pre-scale: (1/8) * log2(e) so attention softmax uses 2^x directly
#define QSCALE 0.18033688011112042f

// device-wide barrier: all GRID blocks co-resident (enforced by launch_bounds+LDS)
__device__ __forceinline__ void gbar(unsigned* bar, int idx) {
    __syncthreads();
    if (threadIdx.x == 0) {
        __threadfence();
        __hip_atomic_fetch_add(bar + idx, 1u, __ATOMIC_ACQ_REL, __HIP_MEMORY_SCOPE_AGENT);
        while (__hip_atomic_load(bar + idx, __ATOMIC_ACQUIRE, __HIP_MEMORY_SCOPE_AGENT) < (unsigned)GRID) {
            __builtin_amdgcn_s_sleep(8);
        }
        __threadfence();
    }
    __syncthreads();
}

// ---------------- Megakernel: GN + wprep | QKV | attention | merge --------
__global__ __launch_bounds__(256, 2) void mega(
        const float* __restrict__ x,
        const float* __restrict__ gamma, const float* __restrict__ beta,
        const float* __restrict__ wq, const float* __restrict__ bq,
        const float* __restrict__ wk, const float* __restrict__ bk,
        const float* __restrict__ wv, const float* __restrict__ bv,
        const float* __restrict__ wo, const float* __restrict__ bo,
        float* __restrict__ out,
        float* __restrict__ part, short* __restrict__ wfrag,
        short* __restrict__ qb, short* __restrict__ kb, short* __restrict__ vt,
        unsigned* __restrict__ obf, float* __restrict__ msb,
        unsigned* __restrict__ bar) {
    __shared__ __align__(16) char shraw[49152];   // 48 KB, reused per phase
    const int bid = blockIdx.x;
    const int t = threadIdx.x;

    // ================= P0: GN partial sums + weight prep =================
    if (bid < 256) {
        float* sA = (float*)shraw;
        float* sB = sA + 256;
        int c = t & 63, rr = t >> 6;
        int p0 = bid * 64;
        float s = 0.f, s2 = 0.f;
        #pragma unroll
        for (int k = 0; k < 16; ++k) {
            float v = x[(size_t)(p0 + rr + 4 * k) * CC + c];
            s += v; s2 += v * v;
        }
        sA[t] = s; sB[t] = s2;
        __syncthreads();
        if (t < 64) {
            float fs  = sA[t] + sA[64 + t] + sA[128 + t] + sA[192 + t];
            float fs2 = sB[t] + sB[64 + t] + sB[128 + t] + sB[192 + t];
            part[bid * 128 + t]      = fs;
            part[bid * 128 + 64 + t] = fs2;
        }
    } else if (bid < 272) {
        const float* mats[3] = {wq, wk, wv};
        int i0 = (bid - 256) * 256 + t;
        for (int e = i0; e < 12288; e += 16 * 256) {
            int m = e >> 12;
            int r = e & 4095;
            int dt = r >> 10, h = (r >> 9) & 1, lane = (r >> 3) & 63, j = r & 7;
            int g = lane >> 4, cl = lane & 15;
            float v = mats[m][(h * 32 + g * 8 + j) * 64 + dt * 16 + cl];
            wfrag[e] = (short)bf16bits(v);
        }
        for (int e = i0; e < 4096; e += 16 * 256) {
            int j = e & 7, lane = (e >> 3) & 63, dt = (e >> 9) & 1, s = e >> 10;
            int hi = lane >> 5, l31 = lane & 31;
            float v = wo[(8 * hi + 16 * s + j) * 64 + dt * 32 + l31];
            wfrag[12288 + e] = (short)bf16bits(v);
        }
    }
    gbar(bar, 0);

    // ================= P1: GN finalize (in-block) + QKV proj =============
    if (bid < 256) {
        unsigned short* vtile = (unsigned short*)shraw;            // 9216 B
        float* sA = (float*)(shraw + 9216);                        // 1024 B
        float* sB = sA + 256;                                      // 1024 B
        float* sScale = sB + 256;                                  // 256 B
        float* sShift = sScale + 64;
        int lane = t & 63, wid = t >> 6;
        int g = lane >> 4, cl = lane & 15;
        int pixblk = bid * 64;
        int pix0 = pixblk + wid * 16;
        int b = pixblk >> 12;
        {
            int c = t & 63, rr = t >> 6;
            float s = 0.f, s2 = 0.f;
            #pragma unroll
            for (int k = 0; k < 16; ++k) {
                int blk = b * 64 + rr + 4 * k;
                s  += part[blk * 128 + c];
                s2 += part[blk * 128 + 64 + c];
            }
            sA[t] = s; sB[t] = s2;
            __syncthreads();
            if (t < 64) {
                sA[t] = sA[t] + sA[64 + t] + sA[128 + t] + sA[192 + t];
                sB[t] = sB[t] + sB[64 + t] + sB[128 + t] + sB[192 + t];
            }
            __syncthreads();
            if (t < 64) {
                int gg = t >> 1;
                float sumg  = sA[gg * 2] + sA[gg * 2 + 1];
                float sum2g = sB[gg * 2] + sB[gg * 2 + 1];
                const float n = (float)(NN * 2);
                float mean = sumg / n;
                float var  = sum2g / n - mean * mean;
                float r = rsqrtf(var + EPS);
                float a = gamma[t] * r;
                sScale[t] = a;
                sShift[t] = beta[t] - mean * a;
            }
            __syncthreads();
        }
        const float* xp = x + (size_t)(pix0 + cl) * CC + g * 8;
        float4 x00 = *(const float4*)(xp);
        float4 x01 = *(const float4*)(xp + 4);
        float4 x10 = *(const float4*)(xp + 32);
        float4 x11 = *(const float4*)(xp + 36);
        float4 s00 = *(const float4*)(&sScale[g * 8]);
        float4 s01 = *(const float4*)(&sScale[g * 8 + 4]);
        float4 s10 = *(const float4*)(&sScale[g * 8 + 32]);
        float4 s11 = *(const float4*)(&sScale[g * 8 + 36]);
        float4 f00 = *(const float4*)(&sShift[g * 8]);
        float4 f01 = *(const float4*)(&sShift[g * 8 + 4]);
        float4 f10 = *(const float4*)(&sShift[g * 8 + 32]);
        float4 f11 = *(const float4*)(&sShift[g * 8 + 36]);

        union { bf16x8 v; unsigned u[4]; } af0, af1;
        af0.u[0] = packbf(x00.x * s00.x + f00.x, x00.y * s00.y + f00.y);
        af0.u[1] = packbf(x00.z * s00.z + f00.z, x00.w * s00.w + f00.w);
        af0.u[2] = packbf(x01.x * s01.x + f01.x, x01.y * s01.y + f01.y);
        af0.u[3] = packbf(x01.z * s01.z + f01.z, x01.w * s01.w + f01.w);
        af1.u[0] = packbf(x10.x * s10.x + f10.x, x10.y * s10.y + f10.y);
        af1.u[1] = packbf(x10.z * s10.z + f10.z, x10.w * s10.w + f10.w);
        af1.u[2] = packbf(x11.x * s11.x + f11.x, x11.y * s11.y + f11.y);
        af1.u[3] = packbf(x11.z * s11.z + f11.z, x11.w * s11.w + f11.w);

        #pragma unroll
        for (int m = 0; m < 3; ++m) {
            const float* bias = (m == 0) ? bq : (m == 1) ? bk : bv;
            #pragma unroll
            for (int dt = 0; dt < 4; ++dt) {
                bf16x8 w0 = *(const bf16x8*)(wfrag + (size_t)(((m * 4 + dt) * 2 + 0) * 64 + lane) * 8);
                bf16x8 w1 = *(const bf16x8*)(wfrag + (size_t)(((m * 4 + dt) * 2 + 1) * 64 + lane) * 8);
                f32x4 z = (f32x4){0.f, 0.f, 0.f, 0.f};
                z = __builtin_amdgcn_mfma_f32_16x16x32_bf16(af0.v, w0, z, 0, 0, 0);
                z = __builtin_amdgcn_mfma_f32_16x16x32_bf16(af1.v, w1, z, 0, 0, 0);
                float bias_d = bias[dt * 16 + cl];
                if (m == 0) {
                    #pragma unroll
                    for (int r = 0; r < 4; ++r)
                        qb[(size_t)(pix0 + 4 * g + r) * CC + dt * 16 + cl] =
                            (short)bf16bits((z[r] + bias_d) * QSCALE);
                } else if (m == 1) {
                    #pragma unroll
                    for (int r = 0; r < 4; ++r)
                        kb[(size_t)(pix0 + 4 * g + r) * CC + dt * 16 + cl] =
                            (short)bf16bits(z[r] + bias_d);
                } else {
                    #pragma unroll
                    for (int r = 0; r < 4; ++r)
                        vtile[(dt * 16 + cl) * 72 + wid * 16 + 4 * g + r] =
                            bf16bits(z[r] + bias_d);
                }
            }
        }
        __syncthreads();
        {
            int d = t >> 2, seg = t & 3;
            uint4 v0 = *(const uint4*)(vtile + d * 72 + seg * 16);
            uint4 v1 = *(const uint4*)(vtile + d * 72 + seg * 16 + 8);
            uint4* dst = (uint4*)(vt + ((size_t)(b * 64 + d)) * NN + pixblk + seg * 16);
            dst[0] = v0; dst[1] = v1;
        }
    }
    gbar(bar, 1);

    // ================= P2: flash attention + fused out-proj ==============
    {
        short* attn_lds = (short*)shraw;    // [3][2][4096] shorts
        const int lane = t & 63;
        const int wid  = t >> 6;            // 0..3
        const int hi  = lane >> 5;
        const int l31 = lane & 31;
        const int r7  = l31 & 7;
        const int kseg   = bid & (KSPLIT - 1);
        const int qblock = bid >> 2;                 // 0..127 (128 q each)
        const int qtile  = qblock * 4 + wid;
        const int b = qblock >> 5;
        const int key0 = kseg * (NN / KSPLIT);

        bf16x8 qf[4];
        const short* qp = qb + (size_t)(qtile * QBLK + l31) * CC + 8 * hi;
        #pragma unroll
        for (int s = 0; s < 4; ++s) qf[s] = *(const bf16x8*)(qp + 16 * s);

        const int srow = t >> 3;
        const int scol = t & 7;
        const short* kS = kb + ((size_t)b * NN + key0) * CC;
        const short* vS = vt + ((size_t)b * CC) * NN + key0;

        f32x16 oacc0, oacc1;
        #pragma unroll
        for (int r = 0; r < 16; ++r) { oacc0[r] = 0.f; oacc1[r] = 0.f; }
        float psum = 0.f;

        auto stage = [&](int ck, int bsel) {
            #pragma unroll
            for (int r = 0; r < 2; ++r) {
                int row = srow + 32 * r;
                const short* src = kS + (size_t)(ck * 64 + row) * CC + (scol ^ (row & 7)) * 8;
                __builtin_amdgcn_global_load_lds(
                    (const __attribute__((address_space(1))) void*)src,
                    (__attribute__((address_space(3))) void*)(attn_lds + bsel * 8192 + (r * 32 + wid * 8) * 64),
                    16, 0, 0);
            }
            #pragma unroll
            for (int r = 0; r < 2; ++r) {
                int row = srow + 32 * r;
                const short* src = vS + (size_t)row * NN + ck * 64 + (scol ^ (row & 7)) * 8;
                __builtin_amdgcn_global_load_lds(
                    (const __attribute__((address_space(1))) void*)src,
                    (__attribute__((address_space(3))) void*)(attn_lds + bsel * 8192 + 4096 + (r * 32 + wid * 8) * 64),
                    16, 0, 0);
            }
        };

        auto subbody = [&](const short* kB, const short* vB, int ks) {
            bf16x8 kf[4];
            #pragma unroll
            for (int s = 0; s < 4; ++s)
                kf[s] = *(const bf16x8*)(kB + (32 * ks + l31) * 64 + ((2 * s + hi) ^ r7) * 8);
            bf16x8 vf0 = *(const bf16x8*)(vB + (l31) * 64      + ((4 * ks + 0 + hi) ^ r7) * 8);
            bf16x8 vf1 = *(const bf16x8*)(vB + (32 + l31) * 64 + ((4 * ks + 0 + hi) ^ r7) * 8);
            bf16x8 vf2 = *(const bf16x8*)(vB + (l31) * 64      + ((4 * ks + 2 + hi) ^ r7) * 8);
            bf16x8 vf3 = *(const bf16x8*)(vB + (32 + l31) * 64 + ((4 * ks + 2 + hi) ^ r7) * 8);
            f32x16 st;
            #pragma unroll
            for (int r = 0; r < 16; ++r) st[r] = 0.f;
            #pragma unroll
            for (int s = 0; s < 4; ++s)
                st = __builtin_amdgcn_mfma_f32_32x32x16_bf16(kf[s], qf[s], st, 0, 0, 0);
            float ps = 0.f;
            #pragma unroll
            for (int r = 0; r < 16; ++r) { st[r] = exp2g(st[r]); ps += st[r]; }
            psum += ps;
            unsigned w[8];
            #pragma unroll
            for (int i = 0; i < 8; ++i) w[i] = cvtpk(st[2 * i], st[2 * i + 1]);
            PSWAP(w[0], w[2]); PSWAP(w[1], w[3]);
            PSWAP(w[4], w[6]); PSWAP(w[5], w[7]);
            union { bf16x8 v; unsigned u[4]; } pa0, pa1;
            pa0.u[0] = w[0]; pa0.u[1] = w[1]; pa0.u[2] = w[2]; pa0.u[3] = w[3];
            pa1.u[0] = w[4]; pa1.u[1] = w[5]; pa1.u[2] = w[6]; pa1.u[3] = w[7];
            oacc0 = __builtin_amdgcn_mfma_f32_32x32x16_bf16(pa0.v, vf0, oacc0, 0, 0, 0);
            oacc1 = __builtin_amdgcn_mfma_f32_32x32x16_bf16(pa0.v, vf1, oacc1, 0, 0, 0);
            oacc0 = __builtin_amdgcn_mfma_f32_32x32x16_bf16(pa1.v, vf2, oacc0, 0, 0, 0);
            oacc1 = __builtin_amdgcn_mfma_f32_32x32x16_bf16(pa1.v, vf3, oacc1, 0, 0, 0);
        };

        stage(0, 0);
        stage(1, 1);
        #pragma unroll 1
        for (int c = 0; c < NCHK - 1; ++c) {
            asm volatile("s_waitcnt vmcnt(4)" ::: "memory");
            __builtin_amdgcn_s_barrier();
            if (c + 2 < NCHK) stage(c + 2, (c + 2) % 3);
            const short* kB = attn_lds + (c % 3) * 8192;
            const short* vB = kB + 4096;
            subbody(kB, vB, 0);
            subbody(kB, vB, 1);
        }
        asm volatile("s_waitcnt vmcnt(0)" ::: "memory");
        __builtin_amdgcn_s_barrier();
        {
            const int c = NCHK - 1;
            const short* kB = attn_lds + (c % 3) * 8192;
            const short* vB = kB + 4096;
            subbody(kB, vB, 0);
            subbody(kB, vB, 1);
        }

        // epilogue: LDS transpose -> Wo -> Z partials
        __syncthreads();
        unsigned* scr = (unsigned*)attn_lds + (size_t)wid * (32 * 36);
        #pragma unroll
        for (int r = 0; r < 16; ++r) {
            int row = (r & 3) + 8 * (r >> 2) + 4 * hi;
            scr[row * 36 + l31] = cvtpk(oacc0[r], oacc1[r]);
        }
        uint4 wa0 = *(const uint4*)(scr + l31 * 36 + 8 * hi);
        uint4 wa1 = *(const uint4*)(scr + l31 * 36 + 8 * hi + 4);
        uint4 wb0_ = *(const uint4*)(scr + l31 * 36 + 16 + 8 * hi);
        uint4 wb1_ = *(const uint4*)(scr + l31 * 36 + 16 + 8 * hi + 4);
        unsigned wA[8] = {wa0.x, wa0.y, wa0.z, wa0.w, wa1.x, wa1.y, wa1.z, wa1.w};
        unsigned wB[8] = {wb0_.x, wb0_.y, wb0_.z, wb0_.w, wb1_.x, wb1_.y, wb1_.z, wb1_.w};
        union { bf16x8 v; unsigned u[4]; } af[4];
        #pragma unroll
        for (int m = 0; m < 4; ++m) {
            af[0].u[m] = (wA[2 * m] & 0xffffu) | (wA[2 * m + 1] << 16);
            af[1].u[m] = (wB[2 * m] & 0xffffu) | (wB[2 * m + 1] << 16);
            af[2].u[m] = (wA[2 * m] >> 16) | (wA[2 * m + 1] & 0xffff0000u);
            af[3].u[m] = (wB[2 * m] >> 16) | (wB[2 * m + 1] & 0xffff0000u);
        }
        const short* w32 = wfrag + 12288;
        f32x16 z0, z1;
        #pragma unroll
        for (int r = 0; r < 16; ++r) { z0[r] = 0.f; z1[r] = 0.f; }
        #pragma unroll
        for (int s = 0; s < 4; ++s) {
            bf16x8 wo0 = *(const bf16x8*)(w32 + (size_t)((s * 2 + 0) * 64 + lane) * 8);
            bf16x8 wo1 = *(const bf16x8*)(w32 + (size_t)((s * 2 + 1) * 64 + lane) * 8);
            z0 = __builtin_amdgcn_mfma_f32_32x32x16_bf16(af[s].v, wo0, z0, 0, 0, 0);
            z1 = __builtin_amdgcn_mfma_f32_32x32x16_bf16(af[s].v, wo1, z1, 0, 0, 0);
        }
        int task = qtile * KSPLIT + kseg;
        unsigned* ob32 = obf + (size_t)task * 1024;
        #pragma unroll
        for (int r = 0; r < 16; ++r) {
            int row = (r & 3) + 8 * (r >> 2) + 4 * hi;
            ob32[row * 32 + l31] = cvtpk(z0[r], z1[r]);
        }
        msb[task * 64 + lane] = psum;
    }
    gbar(bar, 2);

    // ================= P3: elementwise merge + residual ==================
    #pragma unroll 1
    for (int u = bid * 256 + t; u < NPIX * 32; u += GRID * 256) {
        int q = u >> 5, c31 = u & 31;
        int qtile = q >> 5;
        int zbase = (qtile * KSPLIT) * 1024 + (q & 31) * 32 + c31;
        int mbase = (qtile * KSPLIT) * 64 + (q & 31);
        float zlo = 0.f, zhi = 0.f, ssum = 0.f;
        #pragma unroll
        for (int s = 0; s < KSPLIT; ++s) {
            unsigned w = obf[zbase + s * 1024];
            union { unsigned u; float f; } a, b2;
            a.u = w << 16; b2.u = w & 0xffff0000u;
            zlo += a.f; zhi += b2.f;
            ssum += msb[mbase + s * 64] + msb[mbase + s * 64 + 32];
        }
        float inv = 1.f / ssum;
        size_t i0 = (size_t)q * CC + c31;
        out[i0]      = x[i0]      + bo[c31]      + zlo * inv;
        out[i0 + 32] = x[i0 + 32] + bo[c31 + 32] + zhi * inv;
    }
}

extern "C" void kernel_launch(void* const* d_in, const int* in_sizes, int n_in,
                              void* d_out, int out_size, void* d_ws, size_t ws_size,
                              hipStream_t stream) {
    const float* x     = (const float*)d_in[0];
    const float* gamma = (const float*)d_in[1];
    const float* beta  = (const float*)d_in[2];
    const float* wq    = (const float*)d_in[3];
    const float* bq    = (const float*)d_in[4];
    const float* wk    = (const float*)d_in[5];
    const float* bk    = (const float*)d_in[6];
    const float* wv    = (const float*)d_in[7];
    const float* bv    = (const float*)d_in[8];
    const float* wo    = (const float*)d_in[9];
    const float* bo    = (const float*)d_in[10];
    float* out = (float*)d_out;

    unsigned* bar = (unsigned*)d_ws;                     // 64 B (16 u32)
    float* part   = (float*)((char*)d_ws + 64);          // 32768 f32
    short* wfrag  = (short*)(part + 32768);              // 16384 bf16
    short* qb     = wfrag + 16384;
    short* kbp    = qb  + (size_t)NPIX * CC;
    short* vtp    = kbp + (size_t)NPIX * CC;
    unsigned* obf = (unsigned*)(vtp + (size_t)NPIX * CC);    // NQT32*KSPLIT*1024 u32
    float* msb    = (float*)(obf + (size_t)NQT32 * KSPLIT * 1024);

    hipMemsetAsync(bar, 0, 64, stream);
    hipLaunchKernelGGL(mega, dim3(GRID), dim3(256), 0, stream,
                       x, gamma, beta, wq, bq, wk, bk, wv, bv, wo, bo, out,
                       part, wfrag, qb, kbp, vtp, obf, msb, bar);
}

// Round 18
// 44.925 us; speedup vs baseline: 5.3492x; 5.3492x over previous
//
#include <hip/hip_runtime.h>
#include <math.h>

#define BB 4
#define HH 64
#define WW 64
#define CC 64
#define NN (HH*WW)          // 4096 pixels per batch
#define NPIX (BB*NN)        // 16384 total pixels
#define EPS 1e-3f
#define QBLK 32
#define KSPLIT 4
#define NQT32 (NPIX/QBLK)   // 512 query tiles of 32
#define NCHK ((NN/KSPLIT)/64)  // 16 chunks of 64 keys per segment

using bf16x8 = __attribute__((ext_vector_type(8))) short;
using f32x4  = __attribute__((ext_vector_type(4))) float;
using f32x16 = __attribute__((ext_vector_type(16))) float;

__device__ inline unsigned short bf16bits(float f) {
    union { float f; unsigned u; } a; a.f = f;
    unsigned r = a.u + 0x7fffu + ((a.u >> 16) & 1u);   // RNE
    return (unsigned short)(r >> 16);
}
__device__ inline unsigned packbf(float lo, float hi) {
    return (unsigned)bf16bits(lo) | ((unsigned)bf16bits(hi) << 16);
}
__device__ inline unsigned cvtpk(float lo, float hi) {
    unsigned r;
    asm("v_cvt_pk_bf16_f32 %0, %1, %2" : "=v"(r) : "v"(lo), "v"(hi));
    return r;
}
#define PSWAP(a, b) asm("v_permlane32_swap_b32 %0, %1" : "+v"(a), "+v"(b))

// raw 2^x (no libm edge handling; inputs are bounded scores)
__device__ __forceinline__ float exp2g(float x) {
    float r;
    asm("v_exp_f32 %0, %1" : "=v"(r) : "v"(x));
    return r;
}

// Q pre-scale: (1/8) * log2(e) so attention softmax uses 2^x directly
#define QSCALE 0.18033688011112042f

// ---------------- Kernel 1: GroupNorm partial sums + weight prep ----------
__global__ __launch_bounds__(256) void gn_wt(const float* __restrict__ x,
                                             float* __restrict__ part,
                                             const float* __restrict__ wq,
                                             const float* __restrict__ wk,
                                             const float* __restrict__ wv,
                                             const float* __restrict__ wo,
                                             short* __restrict__ wfrag) {
    int t = threadIdx.x;
    if (blockIdx.x < 256) {
        int c = t & 63, rr = t >> 6;
        int p0 = blockIdx.x * 64;
        float s = 0.f, s2 = 0.f;
        #pragma unroll
        for (int k = 0; k < 16; ++k) {
            float v = x[(size_t)(p0 + rr + 4 * k) * CC + c];
            s += v; s2 += v * v;
        }
        __shared__ float sA[256], sB[256];
        sA[t] = s; sB[t] = s2;
        __syncthreads();
        if (t < 64) {
            float fs  = sA[t] + sA[64 + t] + sA[128 + t] + sA[192 + t];
            float fs2 = sB[t] + sB[64 + t] + sB[128 + t] + sB[192 + t];
            part[blockIdx.x * 128 + t]      = fs;
            part[blockIdx.x * 128 + 64 + t] = fs2;
        }
    } else {
        const float* mats[3] = {wq, wk, wv};
        int i0 = (blockIdx.x - 256) * 256 + t;
        for (int e = i0; e < 12288; e += 16 * 256) {
            int m = e >> 12;
            int r = e & 4095;
            int dt = r >> 10, h = (r >> 9) & 1, lane = (r >> 3) & 63, j = r & 7;
            int g = lane >> 4, cl = lane & 15;
            float v = mats[m][(h * 32 + g * 8 + j) * 64 + dt * 16 + cl];
            wfrag[e] = (short)bf16bits(v);
        }
        for (int e = i0; e < 4096; e += 16 * 256) {
            int j = e & 7, lane = (e >> 3) & 63, dt = (e >> 9) & 1, s = e >> 10;
            int hi = lane >> 5, l31 = lane & 31;
            float v = wo[(8 * hi + 16 * s + j) * 64 + dt * 32 + l31];
            wfrag[12288 + e] = (short)bf16bits(v);
        }
    }
}

// ---------------- Kernel 2: GN finalize (in-block) + QKV proj via MFMA ----
__global__ __launch_bounds__(256) void qkv_proj(
        const float* __restrict__ x,
        const float* __restrict__ part,
        const float* __restrict__ gamma,
        const float* __restrict__ beta,
        const short* __restrict__ wfrag,
        const float* __restrict__ bq, const float* __restrict__ bk,
        const float* __restrict__ bv,
        short* __restrict__ qb, short* __restrict__ kb,
        short* __restrict__ vt) {
    __shared__ unsigned short vtile[64 * 72];
    __shared__ float sA[256], sB[256];
    __shared__ float sScale[64], sShift[64];
    int t = threadIdx.x;
    int lane = t & 63, wid = t >> 6;
    int g = lane >> 4, cl = lane & 15;
    int pixblk = blockIdx.x * 64;
    int pix0 = pixblk + wid * 16;
    int b = pixblk >> 12;

    // in-block GroupNorm finalize (redundant per block; part is L2-hot)
    {
        int c = t & 63, rr = t >> 6;
        float s = 0.f, s2 = 0.f;
        #pragma unroll
        for (int k = 0; k < 16; ++k) {
            int blk = b * 64 + rr + 4 * k;
            s  += part[blk * 128 + c];
            s2 += part[blk * 128 + 64 + c];
        }
        sA[t] = s; sB[t] = s2;
        __syncthreads();
        if (t < 64) {
            sA[t] = sA[t] + sA[64 + t] + sA[128 + t] + sA[192 + t];
            sB[t] = sB[t] + sB[64 + t] + sB[128 + t] + sB[192 + t];
        }
        __syncthreads();
        if (t < 64) {
            int gg = t >> 1;
            float sumg  = sA[gg * 2] + sA[gg * 2 + 1];
            float sum2g = sB[gg * 2] + sB[gg * 2 + 1];
            const float n = (float)(NN * 2);
            float mean = sumg / n;
            float var  = sum2g / n - mean * mean;
            float r = rsqrtf(var + EPS);
            float a = gamma[t] * r;
            sScale[t] = a;
            sShift[t] = beta[t] - mean * a;
        }
        __syncthreads();
    }

    const float* xp = x + (size_t)(pix0 + cl) * CC + g * 8;
    float4 x00 = *(const float4*)(xp);
    float4 x01 = *(const float4*)(xp + 4);
    float4 x10 = *(const float4*)(xp + 32);
    float4 x11 = *(const float4*)(xp + 36);
    float4 s00 = *(const float4*)(&sScale[g * 8]);
    float4 s01 = *(const float4*)(&sScale[g * 8 + 4]);
    float4 s10 = *(const float4*)(&sScale[g * 8 + 32]);
    float4 s11 = *(const float4*)(&sScale[g * 8 + 36]);
    float4 f00 = *(const float4*)(&sShift[g * 8]);
    float4 f01 = *(const float4*)(&sShift[g * 8 + 4]);
    float4 f10 = *(const float4*)(&sShift[g * 8 + 32]);
    float4 f11 = *(const float4*)(&sShift[g * 8 + 36]);

    union { bf16x8 v; unsigned u[4]; } af0, af1;
    af0.u[0] = packbf(x00.x * s00.x + f00.x, x00.y * s00.y + f00.y);
    af0.u[1] = packbf(x00.z * s00.z + f00.z, x00.w * s00.w + f00.w);
    af0.u[2] = packbf(x01.x * s01.x + f01.x, x01.y * s01.y + f01.y);
    af0.u[3] = packbf(x01.z * s01.z + f01.z, x01.w * s01.w + f01.w);
    af1.u[0] = packbf(x10.x * s10.x + f10.x, x10.y * s10.y + f10.y);
    af1.u[1] = packbf(x10.z * s10.z + f10.z, x10.w * s10.w + f10.w);
    af1.u[2] = packbf(x11.x * s11.x + f11.x, x11.y * s11.y + f11.y);
    af1.u[3] = packbf(x11.z * s11.z + f11.z, x11.w * s11.w + f11.w);

    #pragma unroll
    for (int m = 0; m < 3; ++m) {
        const float* bias = (m == 0) ? bq : (m == 1) ? bk : bv;
        #pragma unroll
        for (int dt = 0; dt < 4; ++dt) {
            bf16x8 w0 = *(const bf16x8*)(wfrag + (size_t)(((m * 4 + dt) * 2 + 0) * 64 + lane) * 8);
            bf16x8 w1 = *(const bf16x8*)(wfrag + (size_t)(((m * 4 + dt) * 2 + 1) * 64 + lane) * 8);
            f32x4 z = (f32x4){0.f, 0.f, 0.f, 0.f};
            z = __builtin_amdgcn_mfma_f32_16x16x32_bf16(af0.v, w0, z, 0, 0, 0);
            z = __builtin_amdgcn_mfma_f32_16x16x32_bf16(af1.v, w1, z, 0, 0, 0);
            float bias_d = bias[dt * 16 + cl];
            if (m == 0) {
                #pragma unroll
                for (int r = 0; r < 4; ++r)
                    qb[(size_t)(pix0 + 4 * g + r) * CC + dt * 16 + cl] =
                        (short)bf16bits((z[r] + bias_d) * QSCALE);
            } else if (m == 1) {
                #pragma unroll
                for (int r = 0; r < 4; ++r)
                    kb[(size_t)(pix0 + 4 * g + r) * CC + dt * 16 + cl] =
                        (short)bf16bits(z[r] + bias_d);
            } else {
                #pragma unroll
                for (int r = 0; r < 4; ++r)
                    vtile[(dt * 16 + cl) * 72 + wid * 16 + 4 * g + r] =
                        bf16bits(z[r] + bias_d);
            }
        }
    }
    __syncthreads();
    {
        int d = t >> 2, seg = t & 3;
        uint4 v0 = *(const uint4*)(vtile + d * 72 + seg * 16);
        uint4 v1 = *(const uint4*)(vtile + d * 72 + seg * 16 + 8);
        uint4* dst = (uint4*)(vt + ((size_t)(b * 64 + d)) * NN + pixblk + seg * 16);
        dst[0] = v0; dst[1] = v1;
    }
}

// ---------------- Kernel 3: flash attention + fused per-kseg out-proj -----
// grid = 128 qblocks * KSPLIT(4) = 512; block = 4 waves = 256 thr = 128 q.
__global__ __launch_bounds__(256, 2) void attn_flash(
        const short* __restrict__ qb, const short* __restrict__ kb,
        const short* __restrict__ vt, const short* __restrict__ wfrag,
        unsigned* __restrict__ obf, float* __restrict__ msb) {
    __shared__ short lds[3][2][64 * 64];   // [buf][K|V][64 rows][64 shorts]
    const int t = threadIdx.x;
    const int lane = t & 63;
    const int wid  = t >> 6;               // 0..3
    const int hi  = lane >> 5;
    const int l31 = lane & 31;
    const int r7  = l31 & 7;
    const int kseg   = blockIdx.x % KSPLIT;
    const int qblock = blockIdx.x / KSPLIT;       // 0..127 (128 q each)
    const int qtile  = qblock * 4 + wid;          // this wave's 32-q tile
    const int b = qblock >> 5;                    // 32 qblocks per batch
    const int key0 = kseg * (NN / KSPLIT);        // within batch

    // Q B-fragments: lane: q=l31, ch=16s+8hi+j
    bf16x8 qf[4];
    const short* qp = qb + (size_t)(qtile * QBLK + l31) * CC + 8 * hi;
    #pragma unroll
    for (int s = 0; s < 4; ++s) qf[s] = *(const bf16x8*)(qp + 16 * s);

    // staging geometry: 256 threads cover 32 rows x 8 col16-units per round
    const int srow = t >> 3;               // 0..31
    const int scol = t & 7;
    const short* kS = kb + ((size_t)b * NN + key0) * CC;   // K rows: 64 shorts
    const short* vS = vt + ((size_t)b * CC) * NN + key0;   // V^T rows: stride NN

    f32x16 oacc0, oacc1;
    #pragma unroll
    for (int r = 0; r < 16; ++r) { oacc0[r] = 0.f; oacc1[r] = 0.f; }
    float psum = 0.f;

    // 4 global_load_lds per thread per stage (2 K + 2 V), swizzled source
    auto stage = [&](int ck, int bsel) {
        #pragma unroll
        for (int r = 0; r < 2; ++r) {
            int row = srow + 32 * r;
            const short* src = kS + (size_t)(ck * 64 + row) * CC + (scol ^ (row & 7)) * 8;
            __builtin_amdgcn_global_load_lds(
                (const __attribute__((address_space(1))) void*)src,
                (__attribute__((address_space(3))) void*)&lds[bsel][0][(r * 32 + wid * 8) * 64],
                16, 0, 0);
        }
        #pragma unroll
        for (int r = 0; r < 2; ++r) {
            int row = srow + 32 * r;
            const short* src = vS + (size_t)row * NN + ck * 64 + (scol ^ (row & 7)) * 8;
            __builtin_amdgcn_global_load_lds(
                (const __attribute__((address_space(1))) void*)src,
                (__attribute__((address_space(3))) void*)&lds[bsel][1][(r * 32 + wid * 8) * 64],
                16, 0, 0);
        }
    };

    auto subbody = [&](const short* kB, const short* vB, int ks) {
        bf16x8 kf[4];
        #pragma unroll
        for (int s = 0; s < 4; ++s)
            kf[s] = *(const bf16x8*)(kB + (32 * ks + l31) * 64 + ((2 * s + hi) ^ r7) * 8);
        bf16x8 vf0 = *(const bf16x8*)(vB + (l31) * 64      + ((4 * ks + 0 + hi) ^ r7) * 8);
        bf16x8 vf1 = *(const bf16x8*)(vB + (32 + l31) * 64 + ((4 * ks + 0 + hi) ^ r7) * 8);
        bf16x8 vf2 = *(const bf16x8*)(vB + (l31) * 64      + ((4 * ks + 2 + hi) ^ r7) * 8);
        bf16x8 vf3 = *(const bf16x8*)(vB + (32 + l31) * 64 + ((4 * ks + 2 + hi) ^ r7) * 8);
        f32x16 st;
        #pragma unroll
        for (int r = 0; r < 16; ++r) st[r] = 0.f;
        #pragma unroll
        for (int s = 0; s < 4; ++s)
            st = __builtin_amdgcn_mfma_f32_32x32x16_bf16(kf[s], qf[s], st, 0, 0, 0);
        float ps = 0.f;
        #pragma unroll
        for (int r = 0; r < 16; ++r) { st[r] = exp2g(st[r]); ps += st[r]; }
        psum += ps;
        unsigned w[8];
        #pragma unroll
        for (int i = 0; i < 8; ++i) w[i] = cvtpk(st[2 * i], st[2 * i + 1]);
        PSWAP(w[0], w[2]); PSWAP(w[1], w[3]);
        PSWAP(w[4], w[6]); PSWAP(w[5], w[7]);
        union { bf16x8 v; unsigned u[4]; } pa0, pa1;
        pa0.u[0] = w[0]; pa0.u[1] = w[1]; pa0.u[2] = w[2]; pa0.u[3] = w[3];
        pa1.u[0] = w[4]; pa1.u[1] = w[5]; pa1.u[2] = w[6]; pa1.u[3] = w[7];
        oacc0 = __builtin_amdgcn_mfma_f32_32x32x16_bf16(pa0.v, vf0, oacc0, 0, 0, 0);
        oacc1 = __builtin_amdgcn_mfma_f32_32x32x16_bf16(pa0.v, vf1, oacc1, 0, 0, 0);
        oacc0 = __builtin_amdgcn_mfma_f32_32x32x16_bf16(pa1.v, vf2, oacc0, 0, 0, 0);
        oacc1 = __builtin_amdgcn_mfma_f32_32x32x16_bf16(pa1.v, vf3, oacc1, 0, 0, 0);
    };

    // depth-2 pipeline: stages c,c+1 in flight; wait only for c (vmcnt(4))
    stage(0, 0);
    stage(1, 1);
    #pragma unroll 1
    for (int c = 0; c < NCHK - 1; ++c) {
        asm volatile("s_waitcnt vmcnt(4)" ::: "memory");   // stage(c) landed
        __builtin_amdgcn_s_barrier();
        if (c + 2 < NCHK) stage(c + 2, (c + 2) % 3);
        const short* kB = &lds[c % 3][0][0];
        const short* vB = &lds[c % 3][1][0];
        subbody(kB, vB, 0);
        subbody(kB, vB, 1);
    }
    asm volatile("s_waitcnt vmcnt(0)" ::: "memory");
    __builtin_amdgcn_s_barrier();
    {
        const int c = NCHK - 1;
        const short* kB = &lds[c % 3][0][0];
        const short* vB = &lds[c % 3][1][0];
        subbody(kB, vB, 0);
        subbody(kB, vB, 1);
    }

    // ---- epilogue: transpose O tile via LDS, apply Wo, store Z partials ----
    __syncthreads();   // all waves done with K/V buffers; reuse LDS as scratch
    unsigned* scr = (unsigned*)&lds[0][0][0] + (size_t)wid * (32 * 36);
    #pragma unroll
    for (int r = 0; r < 16; ++r) {
        int row = (r & 3) + 8 * (r >> 2) + 4 * hi;     // query row
        scr[row * 36 + l31] = cvtpk(oacc0[r], oacc1[r]);   // (ch l31, ch l31+32)
    }
    // wave-local readback: lane (hi,l31) gathers query l31's channels
    uint4 wa0 = *(const uint4*)(scr + l31 * 36 + 8 * hi);
    uint4 wa1 = *(const uint4*)(scr + l31 * 36 + 8 * hi + 4);
    uint4 wb0_ = *(const uint4*)(scr + l31 * 36 + 16 + 8 * hi);
    uint4 wb1_ = *(const uint4*)(scr + l31 * 36 + 16 + 8 * hi + 4);
    unsigned wA[8] = {wa0.x, wa0.y, wa0.z, wa0.w, wa1.x, wa1.y, wa1.z, wa1.w};
    unsigned wB[8] = {wb0_.x, wb0_.y, wb0_.z, wb0_.w, wb1_.x, wb1_.y, wb1_.z, wb1_.w};
    union { bf16x8 v; unsigned u[4]; } af[4];
    #pragma unroll
    for (int m = 0; m < 4; ++m) {
        af[0].u[m] = (wA[2 * m] & 0xffffu) | (wA[2 * m + 1] << 16);
        af[1].u[m] = (wB[2 * m] & 0xffffu) | (wB[2 * m + 1] << 16);
        af[2].u[m] = (wA[2 * m] >> 16) | (wA[2 * m + 1] & 0xffff0000u);
        af[3].u[m] = (wB[2 * m] >> 16) | (wB[2 * m + 1] & 0xffff0000u);
    }
    const short* w32 = wfrag + 12288;
    f32x16 z0, z1;
    #pragma unroll
    for (int r = 0; r < 16; ++r) { z0[r] = 0.f; z1[r] = 0.f; }
    #pragma unroll
    for (int s = 0; s < 4; ++s) {
        bf16x8 wo0 = *(const bf16x8*)(w32 + (size_t)((s * 2 + 0) * 64 + lane) * 8);
        bf16x8 wo1 = *(const bf16x8*)(w32 + (size_t)((s * 2 + 1) * 64 + lane) * 8);
        z0 = __builtin_amdgcn_mfma_f32_32x32x16_bf16(af[s].v, wo0, z0, 0, 0, 0);
        z1 = __builtin_amdgcn_mfma_f32_32x32x16_bf16(af[s].v, wo1, z1, 0, 0, 0);
    }
    // store Z partials: word(row,l31) = (Z[row][l31], Z[row][l31+32])
    int task = qtile * KSPLIT + kseg;
    unsigned* ob32 = obf + (size_t)task * 1024;
    #pragma unroll
    for (int r = 0; r < 16; ++r) {
        int row = (r & 3) + 8 * (r >> 2) + 4 * hi;
        ob32[row * 32 + l31] = cvtpk(z0[r], z1[r]);
    }
    msb[task * 64 + lane] = psum;
}

// ---------------- Kernel 4: elementwise merge + residual ------------------
__global__ __launch_bounds__(256) void merge_ew(
        const unsigned* __restrict__ obf, const float* __restrict__ msb,
        const float* __restrict__ x, const float* __restrict__ bo,
        float* __restrict__ out) {
    int u = blockIdx.x * 256 + threadIdx.x;      // 0..524287
    int q = u >> 5, c31 = u & 31;
    int qtile = q >> 5;
    int zbase = (qtile * KSPLIT) * 1024 + (q & 31) * 32 + c31;
    int mbase = (qtile * KSPLIT) * 64 + (q & 31);
    float zlo = 0.f, zhi = 0.f, ssum = 0.f;
    #pragma unroll
    for (int s = 0; s < KSPLIT; ++s) {
        unsigned w = obf[zbase + s * 1024];
        union { unsigned u; float f; } a, b2;
        a.u = w << 16; b2.u = w & 0xffff0000u;
        zlo += a.f; zhi += b2.f;
        ssum += msb[mbase + s * 64] + msb[mbase + s * 64 + 32];
    }
    float inv = 1.f / ssum;
    size_t i0 = (size_t)q * CC + c31;
    out[i0]      = x[i0]      + bo[c31]      + zlo * inv;
    out[i0 + 32] = x[i0 + 32] + bo[c31 + 32] + zhi * inv;
}

extern "C" void kernel_launch(void* const* d_in, const int* in_sizes, int n_in,
                              void* d_out, int out_size, void* d_ws, size_t ws_size,
                              hipStream_t stream) {
    const float* x     = (const float*)d_in[0];
    const float* gamma = (const float*)d_in[1];
    const float* beta  = (const float*)d_in[2];
    const float* wq    = (const float*)d_in[3];
    const float* bq    = (const float*)d_in[4];
    const float* wk    = (const float*)d_in[5];
    const float* bk    = (const float*)d_in[6];
    const float* wv    = (const float*)d_in[7];
    const float* bv    = (const float*)d_in[8];
    const float* wo    = (const float*)d_in[9];
    const float* bo    = (const float*)d_in[10];
    float* out = (float*)d_out;

    float* ws    = (float*)d_ws;
    float* part  = ws;                                   // 32768 f32
    short* wfrag = (short*)(part + 32768);               // 16384 bf16
    short* qb    = wfrag + 16384;
    short* kbp   = qb  + (size_t)NPIX * CC;
    short* vtp   = kbp + (size_t)NPIX * CC;
    unsigned* obf = (unsigned*)(vtp + (size_t)NPIX * CC);    // NQT32*KSPLIT*1024 u32
    float* msb   = (float*)(obf + (size_t)NQT32 * KSPLIT * 1024);

    hipLaunchKernelGGL(gn_wt, dim3(272), dim3(256), 0, stream,
                       x, part, wq, wk, wv, wo, wfrag);
    hipLaunchKernelGGL(qkv_proj, dim3(256), dim3(256), 0, stream,
                       x, part, gamma, beta, wfrag, bq, bk, bv, qb, kbp, vtp);
    hipLaunchKernelGGL(attn_flash, dim3(128 * KSPLIT), dim3(256), 0, stream,
                       qb, kbp, vtp, wfrag, obf, msb);
    hipLaunchKernelGGL(merge_ew, dim3(2048), dim3(256), 0, stream,
                       obf, msb, x, bo, out);
}